// Round 1
// baseline (203.642 us; speedup 1.0000x reference)
//
#include <hip/hip_runtime.h>
#include <stdint.h>

// SOM forward: x [4096,64] f32, weights [128,128,64] f32 -> bmus [4096,2] int32.
// argmin_m ||x_b - w_m||. Two-pass:
//   Pass A: approx scores val = ||w||^2 - 2 x.w (fp32 FMA, dot-trick), per
//           (row, 128-m tile) winner stored as sortable-key u64 in d_ws.
//   Pass B: per row, re-score all tile-winners within margin of min in fp64,
//           cast->f32, fsqrt_rn (matches ref's fp32 sqrt tie behavior),
//           tie-break to smaller m. Writes int32 (row, col).

#define SOM_B    4096
#define SOM_F    64
#define SOM_M    16384
#define SOM_COLS 128

__device__ __forceinline__ unsigned enc_f32(float v) {
    unsigned u = __float_as_uint(v);
    return (u & 0x80000000u) ? ~u : (u | 0x80000000u);
}
__device__ __forceinline__ float dec_f32(unsigned e) {
    unsigned u = (e & 0x80000000u) ? (e ^ 0x80000000u) : ~e;
    return __uint_as_float(u);
}
__device__ __forceinline__ unsigned long long umin64(unsigned long long a,
                                                     unsigned long long b) {
    return a < b ? a : b;
}

// ---------------------------------------------------------------------------
// Pass A: 512 blocks = 32 b-tiles x 16 m-chunks (1024 m each, 8 tiles of 128).
// Block tile 128b x 128m, 256 threads, per-thread 8x8 (strided rows tb+16i /
// tm+16j so padded-68 LDS rows are bank-conflict-free for b128 ops).
// ---------------------------------------------------------------------------
__global__ __launch_bounds__(256, 2)
void som_passA(const float* __restrict__ X, const float* __restrict__ W,
               unsigned long long* __restrict__ keys) {
    __shared__ float xs[128 * 68];
    __shared__ float ws[128 * 68];
    __shared__ float wn[128];

    const int tid = threadIdx.x;
    const int tb = tid >> 4;       // 0..15
    const int tm = tid & 15;       // 0..15
    const int btile = blockIdx.x & 31;
    const int chunk = blockIdx.x >> 5;
    const int b0 = btile * 128;
    const int mchunk0 = chunk * 1024;

    // Stage x tile once: rows b0..b0+127, natural [row][64] layout, pad 68.
    {
        const float4* xsrc = reinterpret_cast<const float4*>(X + (size_t)b0 * SOM_F);
#pragma unroll
        for (int j = 0; j < 8; ++j) {
            float4 v = xsrc[tid + j * 256];
            int r = tb + 16 * j;           // (tid + 256j)/16
            *reinterpret_cast<float4*>(&xs[r * 68 + 4 * tm]) = v;
        }
    }

    for (int tile = 0; tile < 8; ++tile) {
        const int mbase = mchunk0 + tile * 128;
        if (tile > 0) __syncthreads();     // protect ws/wn overwrite
        // Stage w tile + wnorm via quarter-wave shuffle reduce.
        {
            const float4* wsrc =
                reinterpret_cast<const float4*>(W + (size_t)mbase * SOM_F);
#pragma unroll
            for (int j = 0; j < 8; ++j) {
                float4 v = wsrc[tid + j * 256];
                int r = tb + 16 * j;
                *reinterpret_cast<float4*>(&ws[r * 68 + 4 * tm]) = v;
                float p = v.x * v.x + v.y * v.y + v.z * v.z + v.w * v.w;
                p += __shfl_xor(p, 1);
                p += __shfl_xor(p, 2);
                p += __shfl_xor(p, 4);
                p += __shfl_xor(p, 8);
                if (tm == 0) wn[r] = p;
            }
        }
        __syncthreads();

        float acc[8][8];
#pragma unroll
        for (int i = 0; i < 8; ++i)
#pragma unroll
            for (int j = 0; j < 8; ++j) acc[i][j] = 0.f;

#pragma unroll 2
        for (int k4 = 0; k4 < 16; ++k4) {
            float4 av[8], wv[8];
#pragma unroll
            for (int i = 0; i < 8; ++i)
                av[i] = *reinterpret_cast<const float4*>(
                    &xs[(tb + 16 * i) * 68 + 4 * k4]);
#pragma unroll
            for (int j = 0; j < 8; ++j)
                wv[j] = *reinterpret_cast<const float4*>(
                    &ws[(tm + 16 * j) * 68 + 4 * k4]);
#pragma unroll
            for (int i = 0; i < 8; ++i)
#pragma unroll
                for (int j = 0; j < 8; ++j) {
                    float s = acc[i][j];
                    s = fmaf(av[i].x, wv[j].x, s);
                    s = fmaf(av[i].y, wv[j].y, s);
                    s = fmaf(av[i].z, wv[j].z, s);
                    s = fmaf(av[i].w, wv[j].w, s);
                    acc[i][j] = s;
                }
        }

        // Per-row winner for this 128-m tile (quarter-wave shuffle reduce).
#pragma unroll
        for (int i = 0; i < 8; ++i) {
            unsigned long long kk = 0xFFFFFFFFFFFFFFFFull;
#pragma unroll
            for (int j = 0; j < 8; ++j) {
                float val = fmaf(-2.f, acc[i][j], wn[tm + 16 * j]);
                unsigned long long key =
                    ((unsigned long long)enc_f32(val) << 32) |
                    (unsigned)(mbase + tm + 16 * j);
                kk = umin64(kk, key);
            }
            kk = umin64(kk, __shfl_xor(kk, 1));
            kk = umin64(kk, __shfl_xor(kk, 2));
            kk = umin64(kk, __shfl_xor(kk, 4));
            kk = umin64(kk, __shfl_xor(kk, 8));
            if (tm == 0) {
                int row = b0 + tb + 16 * i;
                keys[(size_t)row * 128 + chunk * 8 + tile] = kk;
            }
        }
    }
}

// ---------------------------------------------------------------------------
// Pass B: one wave per row. Load 128 tile-winner keys, find min, re-score all
// candidates within margin in fp64, cast f32 + fsqrt_rn, tie-break smaller m.
// ---------------------------------------------------------------------------
__global__ __launch_bounds__(256)
void som_passB(const float* __restrict__ X, const float* __restrict__ W,
               const unsigned long long* __restrict__ keys,
               int* __restrict__ out) {
    const int tid = threadIdx.x;
    const int lane = tid & 63;
    const int row = blockIdx.x * 4 + (tid >> 6);

    const unsigned long long* kr = keys + (size_t)row * 128;
    ulonglong2 p = reinterpret_cast<const ulonglong2*>(kr)[lane];
    unsigned long long k0 = p.x, k1 = p.y;

    unsigned long long kmin = umin64(k0, k1);
#pragma unroll
    for (int s = 1; s < 64; s <<= 1) kmin = umin64(kmin, __shfl_xor(kmin, s));

    float vmin = dec_f32((unsigned)(kmin >> 32));
    unsigned long long thr =
        (((unsigned long long)enc_f32(vmin + 0.05f)) << 32) | 0xFFFFFFFFull;

    float xk = X[(size_t)row * SOM_F + lane];
    float bestv = __int_as_float(0x7F800000);  // +inf
    int bestm = 0x7FFFFFFF;

#pragma unroll
    for (int c = 0; c < 2; ++c) {
        unsigned long long kc = (c == 0) ? k0 : k1;
        unsigned long long mask = __ballot(kc <= thr);
        while (mask) {
            int src = __ffsll(mask) - 1;
            mask &= mask - 1;
            unsigned long long kk = __shfl(kc, src);
            int m = (int)(kk & 0xFFFFFFFFull);
            // fp64 re-score (diff in fp32 to match ref's fp32 diff exactly)
            float wkv = W[(size_t)m * SOM_F + lane];
            float d = xk - wkv;
            double sq = (double)d * (double)d;
#pragma unroll
            for (int s = 1; s < 64; s <<= 1) sq += __shfl_xor(sq, s);
            float tot = (float)sq;
            float val = __fsqrt_rn(tot);
            if (val < bestv || (val == bestv && m < bestm)) {
                bestv = val;
                bestm = m;
            }
        }
    }
    if (lane == 0) {
        out[(size_t)row * 2]     = bestm >> 7;        // row = m / 128
        out[(size_t)row * 2 + 1] = bestm & (SOM_COLS - 1);  // col = m % 128
    }
}

extern "C" void kernel_launch(void* const* d_in, const int* in_sizes, int n_in,
                              void* d_out, int out_size, void* d_ws, size_t ws_size,
                              hipStream_t stream) {
    const float* X = (const float*)d_in[0];   // [4096, 64]
    const float* W = (const float*)d_in[1];   // [128*128, 64]
    int* out = (int*)d_out;                   // [4096, 2] int32
    unsigned long long* keys = (unsigned long long*)d_ws;  // [4096][128] = 4 MB

    som_passA<<<dim3(512), dim3(256), 0, stream>>>(X, W, keys);
    som_passB<<<dim3(1024), dim3(256), 0, stream>>>(X, W, keys, out);
}

// Round 4
// 121.277 us; speedup vs baseline: 1.6792x; 1.6792x over previous
//
#include <hip/hip_runtime.h>
#include <stdint.h>

// SOM forward: x [4096,64] f32, weights [128,128,64] f32 -> bmus [4096,2] int32.
// Three kernels:
//   convert: X,W -> frag-ordered bf16 hi/lo tiles in d_ws + wn=||w||^2 (f32).
//   passA:   MFMA (16x16x32 bf16, 3-pass hi/lo split => ~1e-3 accurate d^2
//            scores val = wn - 2 x.w), per-(row, 64-m group) winner key u64.
//   passB:   per row, exact rescore of group winners within margin 0.05
//            (fp32 diff, fp64 square-sum, f32 sqrt — identical to the
//            validated R1 pass), tie-break smaller m. Writes (row, col).

typedef unsigned short u16;
typedef unsigned int u32;
typedef unsigned long long ull;
typedef __attribute__((ext_vector_type(8))) short bf16x8;
typedef __attribute__((ext_vector_type(4))) float f32x4;

__device__ __forceinline__ u32 enc_f32(float v) {
    u32 u = __float_as_uint(v);
    return (u & 0x80000000u) ? ~u : (u | 0x80000000u);
}
__device__ __forceinline__ float dec_f32(u32 e) {
    u32 u = (e & 0x80000000u) ? (e ^ 0x80000000u) : ~e;
    return __uint_as_float(u);
}
__device__ __forceinline__ ull umin64(ull a, ull b) { return a < b ? a : b; }

__device__ __forceinline__ void stage16(const void* g, void* l) {
    __builtin_amdgcn_global_load_lds(
        (const __attribute__((address_space(1))) u32*)g,
        (__attribute__((address_space(3))) u32*)l, 16, 0, 0);
}

// ---------------------------------------------------------------------------
// convert: unit = (row, half-of-64k). W units: 32768, X units: 8192.
// Frag layout per 16-row tile (ushort units): tile*2048 + s*1024 + p*512 +
// lane*8 + j, lane = (r&15) + ((k&31)>>3)*16, s = k>>5, j = k&7, p in {hi,lo}.
// ---------------------------------------------------------------------------
__global__ __launch_bounds__(256)
void som_convert(const float* __restrict__ X, const float* __restrict__ W,
                 u16* __restrict__ Xc, u16* __restrict__ Wc,
                 float* __restrict__ wn) {
    const int u = blockIdx.x * 256 + threadIdx.x;   // 0..40959
    const bool isW = (u < 32768);
    const int v = isW ? u : (u - 32768);
    const int r = v >> 1, h = v & 1;
    const float* src = (isW ? W : X) + (size_t)r * 64 + h * 32;
    u16* dst = isW ? Wc : Xc;

    float4 f[8];
    const float4* sp = (const float4*)src;
#pragma unroll
    for (int i = 0; i < 8; ++i) f[i] = sp[i];

    float p = 0.f;
#pragma unroll
    for (int i = 0; i < 8; ++i)
        p += f[i].x * f[i].x + f[i].y * f[i].y + f[i].z * f[i].z + f[i].w * f[i].w;

    const int bt = r >> 4, lr = r & 15, s = h;
    u16* base = dst + (size_t)bt * 2048 + s * 1024;
#pragma unroll
    for (int g = 0; g < 4; ++g) {
        float e[8] = { f[2 * g].x, f[2 * g].y, f[2 * g].z, f[2 * g].w,
                       f[2 * g + 1].x, f[2 * g + 1].y, f[2 * g + 1].z, f[2 * g + 1].w };
        u32 hiw[8], low[8];
#pragma unroll
        for (int j = 0; j < 8; ++j) {
            u32 b = __float_as_uint(e[j]);
            hiw[j] = b >> 16;                              // truncated bf16 hi
            float hf = __uint_as_float(b & 0xFFFF0000u);
            float l = e[j] - hf;                           // exact residual
            u32 bl = __float_as_uint(l);
            low[j] = (bl + 0x7FFFu + ((bl >> 16) & 1u)) >> 16;  // RNE bf16 lo
        }
        const int ln = lr + g * 16;
        uint4 qh, ql;
        qh.x = hiw[0] | (hiw[1] << 16); qh.y = hiw[2] | (hiw[3] << 16);
        qh.z = hiw[4] | (hiw[5] << 16); qh.w = hiw[6] | (hiw[7] << 16);
        ql.x = low[0] | (low[1] << 16); ql.y = low[2] | (low[3] << 16);
        ql.z = low[4] | (low[5] << 16); ql.w = low[6] | (low[7] << 16);
        *(uint4*)(base + ln * 8) = qh;
        *(uint4*)(base + 512 + ln * 8) = ql;
    }
    if (isW) {
        p += __shfl_xor(p, 1);       // pair (m,0)/(m,1) are adjacent lanes
        if (h == 0) wn[r] = p;
    }
}

// ---------------------------------------------------------------------------
// passA: grid 512 = 32 b-blocks x 16 m-chunks. 4 waves: wb = wave>>1 (64-row
// half), wm = wave&1 (64-m half). Wave tile 64b x 64m = 4x4 MFMA frags,
// K=64 = 2 ksteps, 3 hi/lo passes -> 96 MFMA / iter / wave. 8 iters of 128 m.
// W staged via linear global_load_lds (frag-ordered source), double-buffered.
// ---------------------------------------------------------------------------
__global__ __launch_bounds__(256, 2)
void som_passA(const u16* __restrict__ Xc, const u16* __restrict__ Wc,
               const float* __restrict__ wn, ull* __restrict__ keys) {
    __shared__ u16 wbuf[2][8][2][2][512];   // [buf][lt][s][p][lane*8] = 64 KB
    const int tid = threadIdx.x;
    const int lane = tid & 63;
    const int wave = tid >> 6;
    const int wb = wave >> 1;
    const int wm = wave & 1;
    const int bblk = blockIdx.x & 31;
    const int chunk = blockIdx.x >> 5;
    const int b0 = bblk * 128;
    const int c15 = lane & 15;

    // Persistent X fragments: 4 row-blocks x 2 ksteps x (hi,lo) = 64 VGPR.
    bf16x8 xh[4][2], xl[4][2];
    {
        const bf16x8* Xf = (const bf16x8*)Xc;
#pragma unroll
        for (int rb = 0; rb < 4; ++rb) {
            const int bt = bblk * 8 + wb * 4 + rb;
#pragma unroll
            for (int s = 0; s < 2; ++s) {
                xh[rb][s] = Xf[bt * 256 + s * 128 + lane];
                xl[rb][s] = Xf[bt * 256 + s * 128 + 64 + lane];
            }
        }
    }

    // Prologue: stage iter 0 into buf 0 (8 x 4 KB, linear).
    {
        const char* src = (const char*)(Wc + (size_t)(chunk * 64) * 2048);
        char* dst = (char*)&wbuf[0][0][0][0][0];
#pragma unroll
        for (int is = 0; is < 8; ++is)
            stage16(src + tid * 16 + is * 4096, dst + tid * 16 + is * 4096);
    }

    for (int it = 0; it < 8; ++it) {
        const int cur = it & 1;
        __syncthreads();   // drains staging vmcnt; all waves' cur buf ready

        const int gt0 = chunk * 64 + it * 8 + wm * 4;  // wave's first m-tile
        float wnv[4];
#pragma unroll
        for (int mt = 0; mt < 4; ++mt)
            wnv[mt] = wn[(gt0 + mt) * 16 + c15];

        if (it < 7) {   // prefetch next tile (lands during compute)
            const char* src =
                (const char*)(Wc + (size_t)(chunk * 64 + (it + 1) * 8) * 2048);
            char* dst = (char*)&wbuf[cur ^ 1][0][0][0][0];
#pragma unroll
            for (int is = 0; is < 8; ++is)
                stage16(src + tid * 16 + is * 4096, dst + tid * 16 + is * 4096);
        }

        f32x4 acc[4][4];
#pragma unroll
        for (int rb = 0; rb < 4; ++rb)
#pragma unroll
            for (int mt = 0; mt < 4; ++mt)
                acc[rb][mt] = (f32x4){0.f, 0.f, 0.f, 0.f};

#pragma unroll
        for (int mt = 0; mt < 4; ++mt) {
            const int lt = wm * 4 + mt;
            const u16* fb = &wbuf[cur][lt][0][0][0];
            bf16x8 bh0 = *(const bf16x8*)(fb + lane * 8);
            bf16x8 bl0 = *(const bf16x8*)(fb + 512 + lane * 8);
            bf16x8 bh1 = *(const bf16x8*)(fb + 1024 + lane * 8);
            bf16x8 bl1 = *(const bf16x8*)(fb + 1536 + lane * 8);
#pragma unroll
            for (int rb = 0; rb < 4; ++rb)
                acc[rb][mt] = __builtin_amdgcn_mfma_f32_16x16x32_bf16(
                    xh[rb][0], bh0, acc[rb][mt], 0, 0, 0);
#pragma unroll
            for (int rb = 0; rb < 4; ++rb)
                acc[rb][mt] = __builtin_amdgcn_mfma_f32_16x16x32_bf16(
                    xh[rb][0], bl0, acc[rb][mt], 0, 0, 0);
#pragma unroll
            for (int rb = 0; rb < 4; ++rb)
                acc[rb][mt] = __builtin_amdgcn_mfma_f32_16x16x32_bf16(
                    xl[rb][0], bh0, acc[rb][mt], 0, 0, 0);
#pragma unroll
            for (int rb = 0; rb < 4; ++rb)
                acc[rb][mt] = __builtin_amdgcn_mfma_f32_16x16x32_bf16(
                    xh[rb][1], bh1, acc[rb][mt], 0, 0, 0);
#pragma unroll
            for (int rb = 0; rb < 4; ++rb)
                acc[rb][mt] = __builtin_amdgcn_mfma_f32_16x16x32_bf16(
                    xh[rb][1], bl1, acc[rb][mt], 0, 0, 0);
#pragma unroll
            for (int rb = 0; rb < 4; ++rb)
                acc[rb][mt] = __builtin_amdgcn_mfma_f32_16x16x32_bf16(
                    xl[rb][1], bh1, acc[rb][mt], 0, 0, 0);
        }

        // Per-(row, 64-m) winner. C/D: col = lane&15, row = (lane>>4)*4+reg.
        const int slot = chunk * 16 + it * 2 + wm;
#pragma unroll
        for (int rb = 0; rb < 4; ++rb) {
#pragma unroll
            for (int rg = 0; rg < 4; ++rg) {
                float va = fmaf(-2.f, acc[rb][0][rg], wnv[0]); int ma = 0;
                float v1 = fmaf(-2.f, acc[rb][1][rg], wnv[1]);
                float v2 = fmaf(-2.f, acc[rb][2][rg], wnv[2]);
                float v3 = fmaf(-2.f, acc[rb][3][rg], wnv[3]);
                if (v1 < va) { va = v1; ma = 1; }
                if (v2 < va) { va = v2; ma = 2; }
                if (v3 < va) { va = v3; ma = 3; }
                ull kk = ((ull)enc_f32(va) << 32) |
                         (u32)((gt0 + ma) * 16 + c15);
                kk = umin64(kk, __shfl_xor(kk, 1));
                kk = umin64(kk, __shfl_xor(kk, 2));
                kk = umin64(kk, __shfl_xor(kk, 4));
                kk = umin64(kk, __shfl_xor(kk, 8));
                if (c15 == 0) {
                    const int row = b0 + wb * 64 + rb * 16 + ((lane >> 4) << 2) + rg;
                    keys[(size_t)row * 256 + slot] = kk;
                }
            }
        }
    }
}

// ---------------------------------------------------------------------------
// passB: one wave per row; 256 group-winner keys/row; exact rescore within
// margin. Numerics identical to validated R1 pass.
// ---------------------------------------------------------------------------
__global__ __launch_bounds__(256)
void som_passB(const float* __restrict__ X, const float* __restrict__ W,
               const ull* __restrict__ keys, int* __restrict__ out) {
    const int tid = threadIdx.x;
    const int lane = tid & 63;
    const int row = blockIdx.x * 4 + (tid >> 6);

    const ull* kr = keys + (size_t)row * 256;
    ulonglong2 pA = ((const ulonglong2*)kr)[lane];
    ulonglong2 pB = ((const ulonglong2*)kr)[lane + 64];
    ull k0 = pA.x, k1 = pA.y, k2 = pB.x, k3 = pB.y;

    ull kmin = umin64(umin64(k0, k1), umin64(k2, k3));
#pragma unroll
    for (int s = 1; s < 64; s <<= 1) kmin = umin64(kmin, __shfl_xor(kmin, s));

    float vmin = dec_f32((u32)(kmin >> 32));
    ull thr = (((ull)enc_f32(vmin + 0.05f)) << 32) | 0xFFFFFFFFull;

    float xk = X[(size_t)row * 64 + lane];
    float bestv = __int_as_float(0x7F800000);  // +inf
    int bestm = 0x7FFFFFFF;

#pragma unroll
    for (int c = 0; c < 4; ++c) {
        ull kc = (c == 0) ? k0 : (c == 1) ? k1 : (c == 2) ? k2 : k3;
        ull mask = __ballot(kc <= thr);
        while (mask) {
            int srcl = __ffsll((unsigned long long)mask) - 1;
            mask &= mask - 1;
            ull kk = __shfl(kc, srcl);
            int m = (int)(kk & 0xFFFFFFFFull);
            float wkv = W[(size_t)m * 64 + lane];
            float d = xk - wkv;
            double sq = (double)d * (double)d;
#pragma unroll
            for (int s = 1; s < 64; s <<= 1) sq += __shfl_xor(sq, s);
            float tot = (float)sq;
            float val = __fsqrt_rn(tot);
            if (val < bestv || (val == bestv && m < bestm)) {
                bestv = val;
                bestm = m;
            }
        }
    }
    if (lane == 0) {
        out[(size_t)row * 2]     = bestm >> 7;   // m / 128
        out[(size_t)row * 2 + 1] = bestm & 127;  // m % 128
    }
}

extern "C" void kernel_launch(void* const* d_in, const int* in_sizes, int n_in,
                              void* d_out, int out_size, void* d_ws, size_t ws_size,
                              hipStream_t stream) {
    const float* X = (const float*)d_in[0];   // [4096, 64]
    const float* W = (const float*)d_in[1];   // [16384, 64]
    int* out = (int*)d_out;                   // [4096, 2] int32

    char* ws = (char*)d_ws;
    u16* Xc   = (u16*)(ws);                              // 1 MB
    u16* Wc   = (u16*)(ws + (1u << 20));                 // 4 MB
    float* wn = (float*)(ws + (5u << 20));               // 64 KB
    ull* keys = (ull*)(ws + (5u << 20) + 65536);         // 8 MB

    som_convert<<<dim3(160), dim3(256), 0, stream>>>(X, W, Xc, Wc, wn);
    som_passA<<<dim3(512), dim3(256), 0, stream>>>(Xc, Wc, wn, keys);
    som_passB<<<dim3(1024), dim3(256), 0, stream>>>(X, W, keys, out);
}

// Round 6
// 92.617 us; speedup vs baseline: 2.1988x; 1.3094x over previous
//
#include <hip/hip_runtime.h>
#include <stdint.h>

// SOM forward: x [4096,64] f32, weights [128,128,64] f32 -> bmus [4096,2] int32.
// Three kernels:
//   convert: X,W -> frag-ordered bf16 hi/lo tiles in d_ws + wn=||w||^2 (f32).
//   passA:   MFMA (16x16x32 bf16, 3-pass hi/lo split => ~3e-4 accurate d^2
//            scores val = wn - 2 x.w). Per-lane RUNNING (val,m) min in
//            registers across all iters (no per-iter cross-lane work);
//            epilogue: one shfl_xor(8) merge -> 64-m-class winner keys,
//            256 keys/row, coalesced u64 stores.
//   passB:   per row, exact rescore of class winners within margin 0.05
//            (fp32 diff, fp64 square-sum, f32 sqrt), tie-break smaller m.
//            Byte-identical to the validated R4 pass.

typedef unsigned short u16;
typedef unsigned int u32;
typedef unsigned long long ull;
typedef __attribute__((ext_vector_type(8))) short bf16x8;
typedef __attribute__((ext_vector_type(4))) float f32x4;

__device__ __forceinline__ u32 enc_f32(float v) {
    u32 u = __float_as_uint(v);
    return (u & 0x80000000u) ? ~u : (u | 0x80000000u);
}
__device__ __forceinline__ float dec_f32(u32 e) {
    u32 u = (e & 0x80000000u) ? (e ^ 0x80000000u) : ~e;
    return __uint_as_float(u);
}
__device__ __forceinline__ ull umin64(ull a, ull b) { return a < b ? a : b; }

__device__ __forceinline__ void stage16(const void* g, void* l) {
    __builtin_amdgcn_global_load_lds(
        (const __attribute__((address_space(1))) u32*)g,
        (__attribute__((address_space(3))) u32*)l, 16, 0, 0);
}

// ---------------------------------------------------------------------------
// convert: unit = (row, half-of-64k). W units: 32768, X units: 8192.
// Frag layout per 16-row tile (ushort units): tile*2048 + s*1024 + p*512 +
// lane*8 + j, lane = (r&15) + ((k&31)>>3)*16, s = k>>5, j = k&7, p in {hi,lo}.
// ---------------------------------------------------------------------------
__global__ __launch_bounds__(256)
void som_convert(const float* __restrict__ X, const float* __restrict__ W,
                 u16* __restrict__ Xc, u16* __restrict__ Wc,
                 float* __restrict__ wn) {
    const int u = blockIdx.x * 256 + threadIdx.x;   // 0..40959
    const bool isW = (u < 32768);
    const int v = isW ? u : (u - 32768);
    const int r = v >> 1, h = v & 1;
    const float* src = (isW ? W : X) + (size_t)r * 64 + h * 32;
    u16* dst = isW ? Wc : Xc;

    float4 f[8];
    const float4* sp = (const float4*)src;
#pragma unroll
    for (int i = 0; i < 8; ++i) f[i] = sp[i];

    float p = 0.f;
#pragma unroll
    for (int i = 0; i < 8; ++i)
        p += f[i].x * f[i].x + f[i].y * f[i].y + f[i].z * f[i].z + f[i].w * f[i].w;

    const int bt = r >> 4, lr = r & 15, s = h;
    u16* base = dst + (size_t)bt * 2048 + s * 1024;
#pragma unroll
    for (int g = 0; g < 4; ++g) {
        float e[8] = { f[2 * g].x, f[2 * g].y, f[2 * g].z, f[2 * g].w,
                       f[2 * g + 1].x, f[2 * g + 1].y, f[2 * g + 1].z, f[2 * g + 1].w };
        u32 hiw[8], low[8];
#pragma unroll
        for (int j = 0; j < 8; ++j) {
            u32 b = __float_as_uint(e[j]);
            hiw[j] = b >> 16;                              // truncated bf16 hi
            float hf = __uint_as_float(b & 0xFFFF0000u);
            float l = e[j] - hf;                           // exact residual
            u32 bl = __float_as_uint(l);
            low[j] = (bl + 0x7FFFu + ((bl >> 16) & 1u)) >> 16;  // RNE bf16 lo
        }
        const int ln = lr + g * 16;
        uint4 qh, ql;
        qh.x = hiw[0] | (hiw[1] << 16); qh.y = hiw[2] | (hiw[3] << 16);
        qh.z = hiw[4] | (hiw[5] << 16); qh.w = hiw[6] | (hiw[7] << 16);
        ql.x = low[0] | (low[1] << 16); ql.y = low[2] | (low[3] << 16);
        ql.z = low[4] | (low[5] << 16); ql.w = low[6] | (low[7] << 16);
        *(uint4*)(base + ln * 8) = qh;
        *(uint4*)(base + 512 + ln * 8) = ql;
    }
    if (isW) {
        p += __shfl_xor(p, 1);       // pair (m,0)/(m,1) are adjacent lanes
        if (h == 0) wn[r] = p;
    }
}

// ---------------------------------------------------------------------------
// passA: grid 512 = 32 b-blocks x 16 m-chunks. 4 waves: wb = wave>>1 (64-row
// half), wm = wave&1 (64-m half). Wave tile 64b x 64m = 4x4 MFMA frags,
// K=64 = 2 ksteps, 3 hi/lo passes -> 96 MFMA / iter / wave. 8 iters of 128 m.
// W staged via linear global_load_lds (frag-ordered source), double-buffered.
// Running per-lane (val,m) min in registers; one cross-lane level at end.
// ---------------------------------------------------------------------------
__global__ __launch_bounds__(256, 2)
void som_passA(const u16* __restrict__ Xc, const u16* __restrict__ Wc,
               const float* __restrict__ wn, ull* __restrict__ keys) {
    __shared__ u16 wbuf[2][8][2][2][512];   // [buf][lt][s][p][lane*8] = 64 KB
    const int tid = threadIdx.x;
    const int lane = tid & 63;
    const int wave = tid >> 6;
    const int wb = wave >> 1;
    const int wm = wave & 1;
    const int bblk = blockIdx.x & 31;
    const int chunk = blockIdx.x >> 5;
    const int b0 = bblk * 128;
    const int c15 = lane & 15;

    // Persistent X fragments: 4 row-blocks x 2 ksteps x (hi,lo) = 64 VGPR.
    bf16x8 xh[4][2], xl[4][2];
    {
        const bf16x8* Xf = (const bf16x8*)Xc;
#pragma unroll
        for (int rb = 0; rb < 4; ++rb) {
            const int bt = bblk * 8 + wb * 4 + rb;
#pragma unroll
            for (int s = 0; s < 2; ++s) {
                xh[rb][s] = Xf[bt * 256 + s * 128 + lane];
                xl[rb][s] = Xf[bt * 256 + s * 128 + 64 + lane];
            }
        }
    }

    // Prologue: stage iter 0 into buf 0 (8 x 4 KB, linear).
    {
        const char* src = (const char*)(Wc + (size_t)(chunk * 64) * 2048);
        char* dst = (char*)&wbuf[0][0][0][0][0];
#pragma unroll
        for (int is = 0; is < 8; ++is)
            stage16(src + tid * 16 + is * 4096, dst + tid * 16 + is * 4096);
    }

    // Running per-lane minima: val + m index per (rb, rg). 32 VGPR.
    float rv[4][4];
    int rm[4][4];
#pragma unroll
    for (int rb = 0; rb < 4; ++rb)
#pragma unroll
        for (int rg = 0; rg < 4; ++rg) {
            rv[rb][rg] = __int_as_float(0x7F800000);  // +inf
            rm[rb][rg] = 0;
        }

    for (int it = 0; it < 8; ++it) {
        const int cur = it & 1;
        __syncthreads();   // drains staging vmcnt; all waves' cur buf ready

        const int gt0 = chunk * 64 + it * 8 + wm * 4;  // wave's first m-tile
        float wnv[4];
#pragma unroll
        for (int mt = 0; mt < 4; ++mt)
            wnv[mt] = wn[(gt0 + mt) * 16 + c15];

        if (it < 7) {   // prefetch next tile (lands during compute)
            const char* src =
                (const char*)(Wc + (size_t)(chunk * 64 + (it + 1) * 8) * 2048);
            char* dst = (char*)&wbuf[cur ^ 1][0][0][0][0];
#pragma unroll
            for (int is = 0; is < 8; ++is)
                stage16(src + tid * 16 + is * 4096, dst + tid * 16 + is * 4096);
        }

        f32x4 acc[4][4];
#pragma unroll
        for (int rb = 0; rb < 4; ++rb)
#pragma unroll
            for (int mt = 0; mt < 4; ++mt)
                acc[rb][mt] = (f32x4){0.f, 0.f, 0.f, 0.f};

#pragma unroll
        for (int mt = 0; mt < 4; ++mt) {
            const int lt = wm * 4 + mt;
            const u16* fb = &wbuf[cur][lt][0][0][0];
            bf16x8 bh0 = *(const bf16x8*)(fb + lane * 8);
            bf16x8 bl0 = *(const bf16x8*)(fb + 512 + lane * 8);
            bf16x8 bh1 = *(const bf16x8*)(fb + 1024 + lane * 8);
            bf16x8 bl1 = *(const bf16x8*)(fb + 1536 + lane * 8);
#pragma unroll
            for (int rb = 0; rb < 4; ++rb)
                acc[rb][mt] = __builtin_amdgcn_mfma_f32_16x16x32_bf16(
                    xh[rb][0], bh0, acc[rb][mt], 0, 0, 0);
#pragma unroll
            for (int rb = 0; rb < 4; ++rb)
                acc[rb][mt] = __builtin_amdgcn_mfma_f32_16x16x32_bf16(
                    xh[rb][0], bl0, acc[rb][mt], 0, 0, 0);
#pragma unroll
            for (int rb = 0; rb < 4; ++rb)
                acc[rb][mt] = __builtin_amdgcn_mfma_f32_16x16x32_bf16(
                    xl[rb][0], bh0, acc[rb][mt], 0, 0, 0);
#pragma unroll
            for (int rb = 0; rb < 4; ++rb)
                acc[rb][mt] = __builtin_amdgcn_mfma_f32_16x16x32_bf16(
                    xh[rb][1], bh1, acc[rb][mt], 0, 0, 0);
#pragma unroll
            for (int rb = 0; rb < 4; ++rb)
                acc[rb][mt] = __builtin_amdgcn_mfma_f32_16x16x32_bf16(
                    xh[rb][1], bl1, acc[rb][mt], 0, 0, 0);
#pragma unroll
            for (int rb = 0; rb < 4; ++rb)
                acc[rb][mt] = __builtin_amdgcn_mfma_f32_16x16x32_bf16(
                    xl[rb][1], bh1, acc[rb][mt], 0, 0, 0);
        }

        // Per-lane running-min update: pure VALU, no cross-lane, no stores.
        // Iteration order => m strictly increasing per lane-class, so strict
        // '<' keeps the smallest m on ties.
#pragma unroll
        for (int rb = 0; rb < 4; ++rb)
#pragma unroll
            for (int rg = 0; rg < 4; ++rg)
#pragma unroll
                for (int mt = 0; mt < 4; ++mt) {
                    float val = fmaf(-2.f, acc[rb][mt][rg], wnv[mt]);
                    int midx = (gt0 + mt) * 16 + c15;
                    bool lt = val < rv[rb][rg];
                    rv[rb][rg] = lt ? val : rv[rb][rg];
                    rm[rb][rg] = lt ? midx : rm[rb][rg];
                }
    }

    // Epilogue: encode, merge c15 <-> c15^8 (64-m classes), coalesced store.
    // C/D layout: col = lane&15, row = (lane>>4)*4 + rg.
#pragma unroll
    for (int rb = 0; rb < 4; ++rb)
#pragma unroll
        for (int rg = 0; rg < 4; ++rg) {
            ull kk = ((ull)enc_f32(rv[rb][rg]) << 32) | (u32)rm[rb][rg];
            kk = umin64(kk, __shfl_xor(kk, 8));
            if ((lane & 8) == 0) {
                const int row = b0 + wb * 64 + rb * 16 + ((lane >> 4) << 2) + rg;
                keys[(size_t)row * 256 + chunk * 16 + wm * 8 + (lane & 7)] = kk;
            }
        }
}

// ---------------------------------------------------------------------------
// passB: one wave per row; 256 class-winner keys/row; exact rescore within
// margin. Numerics identical to validated R1/R4 pass.
// ---------------------------------------------------------------------------
__global__ __launch_bounds__(256)
void som_passB(const float* __restrict__ X, const float* __restrict__ W,
               const ull* __restrict__ keys, int* __restrict__ out) {
    const int tid = threadIdx.x;
    const int lane = tid & 63;
    const int row = blockIdx.x * 4 + (tid >> 6);

    const ull* kr = keys + (size_t)row * 256;
    ulonglong2 pA = ((const ulonglong2*)kr)[lane];
    ulonglong2 pB = ((const ulonglong2*)kr)[lane + 64];
    ull k0 = pA.x, k1 = pA.y, k2 = pB.x, k3 = pB.y;

    ull kmin = umin64(umin64(k0, k1), umin64(k2, k3));
#pragma unroll
    for (int s = 1; s < 64; s <<= 1) kmin = umin64(kmin, __shfl_xor(kmin, s));

    float vmin = dec_f32((u32)(kmin >> 32));
    ull thr = (((ull)enc_f32(vmin + 0.05f)) << 32) | 0xFFFFFFFFull;

    float xk = X[(size_t)row * 64 + lane];
    float bestv = __int_as_float(0x7F800000);  // +inf
    int bestm = 0x7FFFFFFF;

#pragma unroll
    for (int c = 0; c < 4; ++c) {
        ull kc = (c == 0) ? k0 : (c == 1) ? k1 : (c == 2) ? k2 : k3;
        ull mask = __ballot(kc <= thr);
        while (mask) {
            int srcl = __ffsll((unsigned long long)mask) - 1;
            mask &= mask - 1;
            ull kk = __shfl(kc, srcl);
            int m = (int)(kk & 0xFFFFFFFFull);
            float wkv = W[(size_t)m * 64 + lane];
            float d = xk - wkv;
            double sq = (double)d * (double)d;
#pragma unroll
            for (int s = 1; s < 64; s <<= 1) sq += __shfl_xor(sq, s);
            float tot = (float)sq;
            float val = __fsqrt_rn(tot);
            if (val < bestv || (val == bestv && m < bestm)) {
                bestv = val;
                bestm = m;
            }
        }
    }
    if (lane == 0) {
        out[(size_t)row * 2]     = bestm >> 7;   // m / 128
        out[(size_t)row * 2 + 1] = bestm & 127;  // m % 128
    }
}

extern "C" void kernel_launch(void* const* d_in, const int* in_sizes, int n_in,
                              void* d_out, int out_size, void* d_ws, size_t ws_size,
                              hipStream_t stream) {
    const float* X = (const float*)d_in[0];   // [4096, 64]
    const float* W = (const float*)d_in[1];   // [16384, 64]
    int* out = (int*)d_out;                   // [4096, 2] int32

    char* ws = (char*)d_ws;
    u16* Xc   = (u16*)(ws);                              // 1 MB
    u16* Wc   = (u16*)(ws + (1u << 20));                 // 4 MB
    float* wn = (float*)(ws + (5u << 20));               // 64 KB
    ull* keys = (ull*)(ws + (5u << 20) + 65536);         // 8 MB

    som_convert<<<dim3(160), dim3(256), 0, stream>>>(X, W, Xc, Wc, wn);
    som_passA<<<dim3(512), dim3(256), 0, stream>>>(Xc, Wc, wn, keys);
    som_passB<<<dim3(1024), dim3(256), 0, stream>>>(X, W, keys, out);
}